// Round 15
// baseline (253.163 us; speedup 1.0000x reference)
//
#include <hip/hip_runtime.h>

typedef _Float16 f16;
typedef __attribute__((ext_vector_type(4))) _Float16 f16x4;
typedef __attribute__((ext_vector_type(8))) _Float16 f16x8;
typedef __attribute__((ext_vector_type(4))) float f32x4;

#define SC_CONV 0.014731391274719738f   /* 1/sqrt(512*9) */
#define SC_RGB  0.04419417382415922f    /* 1/sqrt(512)   */
#define SC_LIN  0.04419417382415922f    /* 1/sqrt(512)   */
#define SQRT2F  1.4142135623730951f

__device__ inline f32x4 zero_f32x4() {
    f32x4 v;
    #pragma unroll
    for (int i = 0; i < 4; ++i) v[i] = 0.0f;
    return v;
}
__device__ inline void gload_lds16(const void* g, void* l) {
    __builtin_amdgcn_global_load_lds(
        (const __attribute__((address_space(1))) unsigned int*)g,
        (__attribute__((address_space(3))) unsigned int*)l, 16, 0, 0);
}

// ---- prep1: prep_w(+wsq) + styles(wave-per-o) + halos + ctp shell + out init ----------
__global__ __launch_bounds__(256) void k_prep1(
    const float* __restrict__ style,
    const float* __restrict__ m1w, const float* __restrict__ m1b,
    const float* __restrict__ m2w, const float* __restrict__ m2b,
    const float* __restrict__ m3w, const float* __restrict__ m3b,
    float* __restrict__ s1, float* __restrict__ s2, float* __restrict__ s3,
    const float* __restrict__ w1, const float* __restrict__ w2,
    f16* __restrict__ wA1, f16* __restrict__ wA2,
    float* __restrict__ wsq1, float* __restrict__ wsq2,
    f16* __restrict__ xmh, f16* __restrict__ in1h, f16* __restrict__ ctp,
    const float* __restrict__ skiprgb, const float* __restrict__ bias3,
    float* __restrict__ out)
{
    const int bx = blockIdx.x;
    if (bx < 2048) {
        int g = bx * 256 + threadIdx.x;     // over 2*512*512
        int set = g >> 18; int oi = g & 262143;
        const float* w = (set ? w2 : w1) + (size_t)oi * 9;
        f16* wa = set ? wA2 : wA1;
        float* wq = set ? wsq2 : wsq1;
        int o = oi >> 9, i = oi & 511;
        float sw = 0.f;
        #pragma unroll
        for (int t = 0; t < 9; ++t) {
            float v = w[t];
            wa[((size_t)t * 512 + o) * 512 + i] = (f16)v;
            sw += v * v;
        }
        wq[oi] = sw;
    } else if (bx < 2432) {
        const int lane = threadIdx.x & 63, wid = threadIdx.x >> 6;
        const int gw = (bx - 2048) * 4 + wid;
        const int set = gw >> 9, o = gw & 511;
        const float* mw = set == 0 ? m1w : set == 1 ? m2w : m3w;
        const float* mb = set == 0 ? m1b : set == 1 ? m2b : m3b;
        float* outp = set == 0 ? s1 : set == 1 ? s2 : s3;
        const float4 m0 = *(const float4*)(mw + (size_t)o * 512 + lane * 8);
        const float4 m1 = *(const float4*)(mw + (size_t)o * 512 + lane * 8 + 4);
        const float mv[8] = {m0.x, m0.y, m0.z, m0.w, m1.x, m1.y, m1.z, m1.w};
        float acc[8];
        #pragma unroll
        for (int b = 0; b < 8; ++b) {
            const float4 sA = *(const float4*)(style + b * 512 + lane * 8);
            const float4 sB = *(const float4*)(style + b * 512 + lane * 8 + 4);
            acc[b] = mv[0]*sA.x + mv[1]*sA.y + mv[2]*sA.z + mv[3]*sA.w
                   + mv[4]*sB.x + mv[5]*sB.y + mv[6]*sB.z + mv[7]*sB.w;
        }
        #pragma unroll
        for (int b = 0; b < 8; ++b)
            #pragma unroll
            for (int off = 1; off < 64; off <<= 1)
                acc[b] += __shfl_xor(acc[b], off);
        if (lane == 0) {
            const float mbv = mb[o];
            #pragma unroll
            for (int b = 0; b < 8; ++b) outp[b * 512 + o] = acc[b] * SC_LIN + mbv;
        }
    } else if (bx < 2448) {
        const int idx = bx - 2432, b = idx & 7, type = idx >> 3;
        f16x8 z;
        #pragma unroll
        for (int i = 0; i < 8; ++i) z[i] = (_Float16)0.0f;
        if (type == 0) {
            for (int j = threadIdx.x; j < 132 * 64; j += 256) {
                int pix = j >> 6, e = j & 63;
                int r, c;
                if (pix < 34)       { r = 0;            c = pix; }
                else if (pix < 68)  { r = 33;           c = pix - 34; }
                else if (pix < 100) { r = pix - 68 + 1; c = 0; }
                else                { r = pix - 100 + 1; c = 33; }
                *(f16x8*)(xmh + ((((size_t)b * 34 + r) * 34 + c) * 512) + e * 8) = z;
            }
        } else {
            for (int j = threadIdx.x; j < 260 * 64; j += 256) {
                int pix = j >> 6, e = j & 63;
                int r, c;
                if (pix < 66)       { r = 0;             c = pix; }
                else if (pix < 132) { r = 65;            c = pix - 66; }
                else if (pix < 196) { r = pix - 132 + 1; c = 0; }
                else                { r = pix - 196 + 1; c = 65; }
                *(f16x8*)(in1h + ((((size_t)b * 66 + r) * 66 + c) * 512) + e * 8) = z;
            }
        }
    } else if (bx < 2456) {
        const int b = bx - 2448;
        f16x8 z;
        #pragma unroll
        for (int i = 0; i < 8; ++i) z[i] = (_Float16)0.0f;
        for (int j = threadIdx.x; j < 266 * 64; j += 256) {
            int pix = j >> 6, e = j & 63;
            int r, c;
            if (pix < 68)       { r = 0;             c = pix; }
            else if (pix < 136) { r = 66;            c = pix - 68; }
            else if (pix < 201) { r = 1 + (pix - 136); c = 0; }
            else                { r = 1 + (pix - 201); c = 66; }
            *(f16x8*)(ctp + ((((size_t)b * 68 + r) * 68 + c) * 512) + e * 8) = z;
        }
    } else {
        const unsigned g = (unsigned)(bx - 2456) * 256 + threadIdx.x;  // < 98304
        const unsigned b = g / 12288u, rem = g - b * 12288u;
        const unsigned c = rem >> 12, pix = rem & 4095u;
        const int y = (int)(pix >> 6), xx = (int)(pix & 63);
        const float kk[4] = {1.f, 3.f, 3.f, 1.f};
        int sy = y & 1, sx = xx & 1;
        int u0 = ((y + sy) >> 1) - 1, v0 = ((xx + sx) >> 1) - 1;
        float cy0 = kk[sy], cy1 = kk[sy + 2], cx0 = kk[sx], cx1 = kk[sx + 2];
        float sk = 0.f;
        #pragma unroll
        for (int aa = 0; aa < 2; ++aa)
            #pragma unroll
            for (int bb = 0; bb < 2; ++bb) {
                int u = u0 + aa, vv = v0 + bb;
                if (u >= 0 && u < 32 && vv >= 0 && vv < 32)
                    sk += (aa ? cy1 : cy0) * (bb ? cx1 : cx0) *
                          skiprgb[(((size_t)b * 3 + c) * 32 + u) * 32 + vv];
            }
        out[(((size_t)b * 3 + c) * 64 + y) * 64 + xx] = bias3[c] + sk * (1.0f / 16.0f);
    }
}

// ---------------- prep2: demod (reads wsq) + prep_x ----------------
__global__ __launch_bounds__(256) void k_prep2(
    const float* __restrict__ wsq1, const float* __restrict__ s1, float* __restrict__ d1,
    const float* __restrict__ wsq2, const float* __restrict__ s2, float* __restrict__ d2,
    const float* __restrict__ x, f16* __restrict__ xmh)
{
    __shared__ float red[8][4];
    __shared__ float t[32][33];
    const int bx = blockIdx.x;
    if (bx < 1024) {
        const int o = bx & 511, set = bx >> 9;
        const float* wq = set ? wsq2 : wsq1;
        const float* s = set ? s2 : s1;
        float* d = set ? d2 : d1;
        float acc[8] = {0,0,0,0,0,0,0,0};
        for (int i = threadIdx.x; i < 512; i += 256) {
            const float sw = wq[(size_t)o * 512 + i];
            #pragma unroll
            for (int b = 0; b < 8; ++b) { float sv = s[b * 512 + i]; acc[b] += sv * sv * sw; }
        }
        const int lane = threadIdx.x & 63, wid = threadIdx.x >> 6;
        #pragma unroll
        for (int b = 0; b < 8; ++b)
            #pragma unroll
            for (int off = 1; off < 64; off <<= 1)
                acc[b] += __shfl_xor(acc[b], off);
        if (lane == 0) {
            #pragma unroll
            for (int b = 0; b < 8; ++b) red[b][wid] = acc[b];
        }
        __syncthreads();
        if (threadIdx.x < 8) {
            float s4 = red[threadIdx.x][0] + red[threadIdx.x][1] + red[threadIdx.x][2] + red[threadIdx.x][3];
            d[threadIdx.x * 512 + o] = rsqrtf(s4 * (SC_CONV * SC_CONV) + 1e-8f);
        }
    } else {
        const int idx = bx - 1024, u = idx & 31, b = idx >> 5;
        int tx = threadIdx.x & 31, ty = threadIdx.x >> 5;   // 32 x 8
        for (int ic = 0; ic < 512; ic += 32) {
            #pragma unroll
            for (int k = 0; k < 4; ++k) {
                int i = ic + ty + 8 * k;
                t[ty + 8 * k][tx] = x[(((size_t)b * 512 + i) * 32 + u) * 32 + tx];
            }
            __syncthreads();
            #pragma unroll
            for (int k = 0; k < 4; ++k) {
                int v = ty + 8 * k;
                int i = ic + tx;
                float sv = s1[b * 512 + i] * SC_CONV;
                xmh[(((size_t)b * 34 + u + 1) * 34 + v + 1) * 512 + i] = (f16)(t[tx][v] * sv);
            }
            __syncthreads();
        }
    }
}

// ---------------- conv1: batch-merged flattened 256-tile, two-phase pipeline ------------
__global__ __launch_bounds__(512, 2) void k_conv1m(
    const f16* __restrict__ xmh, const f16* __restrict__ wA1, f16* __restrict__ ctp)
{
    const int gid = blockIdx.x;
    int ph, tbase;
    if (gid < 70)       { ph = 0; tbase = 0; }
    else if (gid < 136) { ph = 1; tbase = 70; }
    else if (gid < 202) { ph = 2; tbase = 136; }
    else                { ph = 3; tbase = 202; }
    const int p = ph >> 1, q = ph & 1;
    const int Nn = q ? 32 : 33;
    const unsigned npos = (unsigned)((p ? 32 : 33) * Nn);
    const unsigned ntot = npos * 8;
    const int tiles_n = (int)((ntot + 255) >> 8);
    int t = gid - tbase;
    const int mB = (t >= tiles_n) ? 256 : 0;
    if (t >= tiles_n) t -= tiles_n;
    const unsigned posB = (unsigned)t * 256;
    const int ntx = q ? 1 : 2;
    const int ntaps = (p ? 1 : 2) * ntx;
    const int ktsteps = ntaps * 8;

    __shared__ f16 LA[2][16384];
    __shared__ f16 LB[2][16384];
    const int tid = threadIdx.x, lane = tid & 63, wid = tid >> 6;
    const int wm = wid >> 2, wn = wid & 3;      // 2 M-waves x 4 N-waves
    const int lr = lane & 15, lk = lane >> 4;

    f32x4 acc[8][4];
    #pragma unroll
    for (int mf = 0; mf < 8; ++mf)
        #pragma unroll
        for (int nf = 0; nf < 4; ++nf) acc[mf][nf] = zero_f32x4();

    int aoff[4], boff[4], ldst[4];
    #pragma unroll
    for (int c = 0; c < 4; ++c) {
        const int idx = c * 512 + tid;
        const int row = idx >> 3, sl = idx & 7, ssl = sl ^ (row & 7);
        ldst[c] = idx * 16;
        aoff[c] = (mB + row) * 512 + ssl * 8;
        unsigned pos = posB + (unsigned)row;
        if (pos > ntot - 1) pos = ntot - 1;
        const unsigned bb = pos / npos, rr = pos - bb * npos;
        const unsigned u = rr / (unsigned)Nn, v = rr - u * (unsigned)Nn;
        boff[c] = (int)(((bb * 34 + u + 1) * 34 + v + 1) * 512) + ssl * 8;
    }

    int raA[8], raB[4];
    #pragma unroll
    for (int mf = 0; mf < 8; ++mf) {
        const int R = wm * 128 + mf * 16 + lr;
        raA[mf] = R * 128 + ((lk ^ (R & 7)) * 16);
    }
    #pragma unroll
    for (int nf = 0; nf < 4; ++nf) {
        const int R = wn * 64 + nf * 16 + lr;
        raB[nf] = R * 128 + ((lk ^ (R & 7)) * 16);
    }

    auto stageA = [&](int kt, int d) {
        const int tt = kt >> 3, icb = (kt & 7) << 6;
        const int ay = (ntx == 2) ? (tt >> 1) : tt;
        const int ax = (ntx == 2) ? (tt & 1) : 0;
        const f16* base = wA1 + (size_t)((p + 2 * ay) * 3 + (q + 2 * ax)) * 262144 + icb;
        char* dst = (char*)LA[d];
        #pragma unroll
        for (int c = 0; c < 4; ++c)
            gload_lds16(base + aoff[c], dst + ldst[c]);
    };
    auto stageB = [&](int kt, int d) {
        const int tt = kt >> 3, icb = (kt & 7) << 6;
        const int ay = (ntx == 2) ? (tt >> 1) : tt;
        const int ax = (ntx == 2) ? (tt & 1) : 0;
        const f16* base = xmh - (long)(ay * 34 + ax) * 512 + icb;
        char* dst = (char*)LB[d];
        #pragma unroll
        for (int c = 0; c < 4; ++c)
            gload_lds16(base + boff[c], dst + ldst[c]);
    };

    stageB(0, 0);
    stageA(0, 0);
    for (int kt = 0; kt < ktsteps; ++kt) {
        const int d = kt & 1;
        asm volatile("s_waitcnt vmcnt(0)" ::: "memory");
        __builtin_amdgcn_s_barrier();
        const char* A = (const char*)LA[d];
        const char* Bm = (const char*)LB[d];
        f16x8 bf[4][2], af[4][2];
        #pragma unroll
        for (int nf = 0; nf < 4; ++nf) {
            bf[nf][0] = *(const f16x8*)(Bm + raB[nf]);
            bf[nf][1] = *(const f16x8*)(Bm + (raB[nf] ^ 64));
        }
        #pragma unroll
        for (int mf = 0; mf < 4; ++mf) {
            af[mf][0] = *(const f16x8*)(A + raA[mf]);
            af[mf][1] = *(const f16x8*)(A + (raA[mf] ^ 64));
        }
        if (kt + 1 < ktsteps) stageB(kt + 1, d ^ 1);
        asm volatile("s_waitcnt lgkmcnt(0)" ::: "memory");
        __builtin_amdgcn_sched_barrier(0);
        __builtin_amdgcn_s_setprio(1);
        #pragma unroll
        for (int mf = 0; mf < 4; ++mf)
            #pragma unroll
            for (int nf = 0; nf < 4; ++nf) {
                acc[mf][nf] = __builtin_amdgcn_mfma_f32_16x16x32_f16(
                    af[mf][0], bf[nf][0], acc[mf][nf], 0, 0, 0);
                acc[mf][nf] = __builtin_amdgcn_mfma_f32_16x16x32_f16(
                    af[mf][1], bf[nf][1], acc[mf][nf], 0, 0, 0);
            }
        __builtin_amdgcn_s_setprio(0);
        #pragma unroll
        for (int mf = 0; mf < 4; ++mf) {
            af[mf][0] = *(const f16x8*)(A + raA[mf + 4]);
            af[mf][1] = *(const f16x8*)(A + (raA[mf + 4] ^ 64));
        }
        if (kt + 1 < ktsteps) stageA(kt + 1, d ^ 1);
        asm volatile("s_waitcnt lgkmcnt(0)" ::: "memory");
        __builtin_amdgcn_sched_barrier(0);
        __builtin_amdgcn_s_setprio(1);
        #pragma unroll
        for (int mf = 0; mf < 4; ++mf)
            #pragma unroll
            for (int nf = 0; nf < 4; ++nf) {
                acc[mf + 4][nf] = __builtin_amdgcn_mfma_f32_16x16x32_f16(
                    af[mf][0], bf[nf][0], acc[mf + 4][nf], 0, 0, 0);
                acc[mf + 4][nf] = __builtin_amdgcn_mfma_f32_16x16x32_f16(
                    af[mf][1], bf[nf][1], acc[mf + 4][nf], 0, 0, 0);
            }
        __builtin_amdgcn_s_setprio(0);
    }

    // epilogue: coalesced f16x4 NHWC stores
    #pragma unroll
    for (int nf = 0; nf < 4; ++nf) {
        const int c = wn * 64 + nf * 16 + lr;
        const unsigned pos = posB + (unsigned)c;
        if (pos >= ntot) continue;
        const unsigned bb = pos / npos, rr = pos - bb * npos;
        const unsigned u = rr / (unsigned)Nn, v = rr - u * (unsigned)Nn;
        const int row = 1 + 2 * (int)u + p, col = 1 + 2 * (int)v + q;
        f16* dst = ctp + (((size_t)bb * 68 + row) * 68 + col) * 512;
        #pragma unroll
        for (int mf = 0; mf < 8; ++mf) {
            const int ob = mB + wm * 128 + mf * 16 + lk * 4;
            f16x4 st;
            #pragma unroll
            for (int r = 0; r < 4; ++r) st[r] = (f16)acc[mf][nf][r];
            *(f16x4*)(dst + ob) = st;
        }
    }
}

// ---- blur1 (NHWC): 2-row blocks, vertical reuse, channel-on-lanes, no LDS --------------
__global__ __launch_bounds__(256) void k_blur1(
    const f16* __restrict__ ctp, const float* __restrict__ d1,
    const float* __restrict__ noise1, const float* __restrict__ nw1,
    const float* __restrict__ bias1, const float* __restrict__ s2,
    f16* __restrict__ in1h)
{
    const int y0 = blockIdx.x * 2, b = blockIdx.y;
    const int tx = threadIdx.x & 63, xg = threadIdx.x >> 6;
    const int ch = tx * 8, x0 = xg * 16;
    const f16* base = ctp + ((size_t)(b * 68 + y0) * 68) * 512 + ch;   // row y0, col 0

    float d1v[8], b1v[8], s2v[8];
    {
        const float4 a0 = *(const float4*)(d1 + b * 512 + ch);
        const float4 a1 = *(const float4*)(d1 + b * 512 + ch + 4);
        const float4 c0 = *(const float4*)(bias1 + ch);
        const float4 c1 = *(const float4*)(bias1 + ch + 4);
        const float4 e0 = *(const float4*)(s2 + b * 512 + ch);
        const float4 e1 = *(const float4*)(s2 + b * 512 + ch + 4);
        d1v[0]=a0.x; d1v[1]=a0.y; d1v[2]=a0.z; d1v[3]=a0.w;
        d1v[4]=a1.x; d1v[5]=a1.y; d1v[6]=a1.z; d1v[7]=a1.w;
        b1v[0]=c0.x; b1v[1]=c0.y; b1v[2]=c0.z; b1v[3]=c0.w;
        b1v[4]=c1.x; b1v[5]=c1.y; b1v[6]=c1.z; b1v[7]=c1.w;
        s2v[0]=e0.x; s2v[1]=e0.y; s2v[2]=e0.z; s2v[3]=e0.w;
        s2v[4]=e1.x; s2v[5]=e1.y; s2v[6]=e1.z; s2v[7]=e1.w;
    }
    const float nw = nw1[0];
    const float* nrow0 = noise1 + ((size_t)b * 64 + y0) * 64;
    const float* nrow1 = nrow0 + 64;

    float cs[4][2][8];
    #define LOADCOL(cc, slot)                                                   \
        do {                                                                    \
            f16x8 v0 = *(const f16x8*)(base + ((size_t)(0 * 68 + (cc))) * 512); \
            f16x8 v1 = *(const f16x8*)(base + ((size_t)(1 * 68 + (cc))) * 512); \
            f16x8 v2 = *(const f16x8*)(base + ((size_t)(2 * 68 + (cc))) * 512); \
            f16x8 v3 = *(const f16x8*)(base + ((size_t)(3 * 68 + (cc))) * 512); \
            f16x8 v4 = *(const f16x8*)(base + ((size_t)(4 * 68 + (cc))) * 512); \
            _Pragma("unroll")                                                   \
            for (int k = 0; k < 8; ++k) {                                       \
                float f0=(float)v0[k], f1=(float)v1[k], f2=(float)v2[k];        \
                float f3=(float)v3[k], f4=(float)v4[k];                         \
                cs[slot][0][k] = f0 + 3.f*f1 + 3.f*f2 + f3;                     \
                cs[slot][1][k] = f1 + 3.f*f2 + 3.f*f3 + f4;                     \
            }                                                                   \
        } while (0)

    LOADCOL(x0 + 0, 0);
    LOADCOL(x0 + 1, 1);
    LOADCOL(x0 + 2, 2);
    #pragma unroll
    for (int xi = 0; xi < 16; ++xi) {
        LOADCOL(x0 + xi + 3, ((xi + 3) & 3));
        const int x = x0 + xi;
        const float nz0 = nw * nrow0[x];
        const float nz1 = nw * nrow1[x];
        f16x8 st0, st1;
        #pragma unroll
        for (int k = 0; k < 8; ++k) {
            float s0 = (cs[xi & 3][0][k] + cs[(xi + 3) & 3][0][k])
                     + 3.f * (cs[(xi + 1) & 3][0][k] + cs[(xi + 2) & 3][0][k]);
            float v0 = s0 * (1.0f / 16.0f) * d1v[k] + nz0 + b1v[k];
            v0 = (v0 > 0.f ? v0 : 0.2f * v0) * SQRT2F;
            st0[k] = (f16)(v0 * s2v[k] * SC_CONV);
            float s1r = (cs[xi & 3][1][k] + cs[(xi + 3) & 3][1][k])
                      + 3.f * (cs[(xi + 1) & 3][1][k] + cs[(xi + 2) & 3][1][k]);
            float v1 = s1r * (1.0f / 16.0f) * d1v[k] + nz1 + b1v[k];
            v1 = (v1 > 0.f ? v1 : 0.2f * v1) * SQRT2F;
            st1[k] = (f16)(v1 * s2v[k] * SC_CONV);
        }
        *(f16x8*)(in1h + (((size_t)(b * 66 + 1 + y0) * 66) + 1 + x) * 512 + ch) = st0;
        *(f16x8*)(in1h + (((size_t)(b * 66 + 2 + y0) * 66) + 1 + x) * 512 + ch) = st1;
    }
    #undef LOADCOL
}

// ---- conv2: 256x256 tile, 8-wave, K-half phases with counted vmcnt(4) (T3+T4) ----------
// LDS: 2 dbuf x 2 khalf per operand, 16KB each (total 128KB). Per phase (K=32):
// vmcnt(4) -> barrier -> 12 ds_read -> stage next tile's same-khalf (4 loads) ->
// lgkmcnt(0) -> 32 MFMA. Loads span a full K-tile before use; never drain to 0.
// 64B-row swizzle: slot ^= (row>>1)&3 on BOTH source and ds_read (rule #21).
__global__ __launch_bounds__(512, 2) void k_conv2_8p(
    const f16* __restrict__ in1h, const f16* __restrict__ wA2,
    const float* __restrict__ d2, const float* __restrict__ noise2,
    const float* __restrict__ nw2, const float* __restrict__ bias2,
    const float* __restrict__ s3, const float* __restrict__ w3,
    float* __restrict__ out)
{
    const int b = blockIdx.z, mB = blockIdx.y * 256, nT = blockIdx.x;
    const int y0 = nT * 4;       // 256 pixels = rows y0..y0+3
    __shared__ f16 LA[4][8192];  // [dbuf*2 + khalf]: 256 rows x 32 K
    __shared__ f16 LB[4][8192];
    const int tid = threadIdx.x, lane = tid & 63, wid = tid >> 6;
    const int wm = wid >> 2, wn = wid & 3;      // 2 M-waves x 4 N-waves
    const int lr = lane & 15, lk = lane >> 4;

    f32x4 acc[8][4];
    #pragma unroll
    for (int mf = 0; mf < 8; ++mf)
        #pragma unroll
        for (int nf = 0; nf < 4; ++nf) acc[mf][nf] = zero_f32x4();

    // staging: 2 chunks per operand-half per thread (half = 256 rows x 32 K = 16KB)
    int aoff[2], boff[2], ldst[2];
    #pragma unroll
    for (int c = 0; c < 2; ++c) {
        const int idx = c * 512 + tid;          // 0..1023
        const int row = idx >> 2, sl = idx & 3;
        const int ks = sl ^ ((row >> 1) & 3);   // pre-swizzled source K-group
        ldst[c] = idx * 16;
        aoff[c] = (mB + row) * 512 + ks * 8;
        const int py = y0 + (row >> 6), px = row & 63;
        boff[c] = ((b * 66 + 1 + py) * 66 + 1 + px) * 512 + ks * 8;
    }

    // ds_read byte addrs within a 16KB half (row stride 64B)
    int raA[8], raB[4];
    #pragma unroll
    for (int mf = 0; mf < 8; ++mf) {
        const int R = wm * 128 + mf * 16 + lr;
        raA[mf] = R * 64 + ((lk ^ ((R >> 1) & 3)) * 16);
    }
    #pragma unroll
    for (int nf = 0; nf < 4; ++nf) {
        const int R = wn * 64 + nf * 16 + lr;
        raB[nf] = R * 64 + ((lk ^ ((R >> 1) & 3)) * 16);
    }

    auto stage = [&](int kt, int h) {          // 4 loads: 2 A + 2 B, same khalf h
        const int d = kt & 1;
        const int tap = kt >> 3, icb = ((kt & 7) << 6) + h * 32;
        const f16* Ab = wA2 + (size_t)tap * 262144 + icb;
        const int dy = tap / 3 - 1, dx = tap - (tap / 3) * 3 - 1;
        const f16* Bb = in1h + (dy * 66 + dx) * 512 + icb;
        char* Ad = (char*)LA[d * 2 + h];
        char* Bd = (char*)LB[d * 2 + h];
        gload_lds16(Ab + aoff[0], Ad + ldst[0]);
        gload_lds16(Ab + aoff[1], Ad + ldst[1]);
        gload_lds16(Bb + boff[0], Bd + ldst[0]);
        gload_lds16(Bb + boff[1], Bd + ldst[1]);
    };

    auto phase = [&](int kt, int h, bool doStage, int vm) {
        if (vm == 4) asm volatile("s_waitcnt vmcnt(4)" ::: "memory");
        else         asm volatile("s_waitcnt vmcnt(0)" ::: "memory");
        __builtin_amdgcn_s_barrier();
        const int d = kt & 1;
        const char* A  = (const char*)LA[d * 2 + h];
        const char* Bm = (const char*)LB[d * 2 + h];
        f16x8 af[8], bf[4];
        #pragma unroll
        for (int nf = 0; nf < 4; ++nf) bf[nf] = *(const f16x8*)(Bm + raB[nf]);
        #pragma unroll
        for (int mf = 0; mf < 8; ++mf) af[mf] = *(const f16x8*)(A + raA[mf]);
        if (doStage) stage(kt + 1, h);
        asm volatile("s_waitcnt lgkmcnt(0)" ::: "memory");
        __builtin_amdgcn_sched_barrier(0);
        __builtin_amdgcn_s_setprio(1);
        #pragma unroll
        for (int mf = 0; mf < 8; ++mf)
            #pragma unroll
            for (int nf = 0; nf < 4; ++nf)
                acc[mf][nf] = __builtin_amdgcn_mfma_f32_16x16x32_f16(
                    af[mf], bf[nf], acc[mf][nf], 0, 0, 0);
        __builtin_amdgcn_s_setprio(0);
    };

    stage(0, 0);   // klo(0): outstanding 4
    stage(0, 1);   // khi(0): outstanding 8
    for (int kt = 0; kt < 71; ++kt) {
        phase(kt, 0, true, 4);
        phase(kt, 1, true, 4);
    }
    phase(71, 0, false, 4);
    phase(71, 1, false, 0);

    // fused epilogue: demod+noise+bias+lrelu+s3 fold, then partial RGB dot + atomicAdd
    const float* d2b = d2 + b * 512;
    const float* s3b = s3 + b * 512;
    const float nw = nw2[0];
    float p3[4][3];
    #pragma unroll
    for (int nf = 0; nf < 4; ++nf)
        #pragma unroll
        for (int c = 0; c < 3; ++c) p3[nf][c] = 0.f;
    #pragma unroll
    for (int mf = 0; mf < 8; ++mf) {
        const int ob = mB + wm * 128 + mf * 16 + lk * 4;
        const float4 dv = *(const float4*)(d2b + ob);
        const float4 bv = *(const float4*)(bias2 + ob);
        const float4 sv = *(const float4*)(s3b + ob);
        const float4 w0 = *(const float4*)(w3 + 0 * 512 + ob);
        const float4 w1v = *(const float4*)(w3 + 1 * 512 + ob);
        const float4 w2v = *(const float4*)(w3 + 2 * 512 + ob);
        const float dd[4] = {dv.x, dv.y, dv.z, dv.w};
        const float bb[4] = {bv.x, bv.y, bv.z, bv.w};
        const float ss[4] = {sv.x, sv.y, sv.z, sv.w};
        const float w0r[4] = {w0.x, w0.y, w0.z, w0.w};
        const float w1r[4] = {w1v.x, w1v.y, w1v.z, w1v.w};
        const float w2r[4] = {w2v.x, w2v.y, w2v.z, w2v.w};
        #pragma unroll
        for (int nf = 0; nf < 4; ++nf) {
            const int c = wn * 64 + nf * 16 + lr;
            const int py = y0 + (c >> 6), px = c & 63;
            const float nz = nw * noise2[((size_t)b * 64 + py) * 64 + px];
            #pragma unroll
            for (int r = 0; r < 4; ++r) {
                float v = acc[mf][nf][r] * dd[r] + nz + bb[r];
                v = (v > 0.f ? v : 0.2f * v) * SQRT2F;
                v *= ss[r] * SC_RGB;
                p3[nf][0] += v * w0r[r];
                p3[nf][1] += v * w1r[r];
                p3[nf][2] += v * w2r[r];
            }
        }
    }
    #pragma unroll
    for (int nf = 0; nf < 4; ++nf)
        #pragma unroll
        for (int c = 0; c < 3; ++c) {
            float v = p3[nf][c];
            v += __shfl_xor(v, 16);
            v += __shfl_xor(v, 32);
            p3[nf][c] = v;
        }
    if (lk == 0) {
        #pragma unroll
        for (int nf = 0; nf < 4; ++nf) {
            const int c = wn * 64 + nf * 16 + lr;
            const int py = y0 + (c >> 6), px = c & 63;
            #pragma unroll
            for (int ch = 0; ch < 3; ++ch)
                atomicAdd(out + (((size_t)b * 3 + ch) * 64 + py) * 64 + px, p3[nf][ch]);
        }
    }
}

extern "C" void kernel_launch(void* const* d_in, const int* in_sizes, int n_in,
                              void* d_out, int out_size, void* d_ws, size_t ws_size,
                              hipStream_t stream)
{
    const float* x       = (const float*)d_in[0];
    const float* style   = (const float*)d_in[1];
    const float* skiprgb = (const float*)d_in[2];
    const float* noise1  = (const float*)d_in[3];
    const float* noise2  = (const float*)d_in[4];
    const float* w1      = (const float*)d_in[5];
    const float* m1w     = (const float*)d_in[6];
    const float* m1b     = (const float*)d_in[7];
    const float* bias1   = (const float*)d_in[8];
    const float* nw1     = (const float*)d_in[9];
    const float* w2      = (const float*)d_in[10];
    const float* m2w     = (const float*)d_in[11];
    const float* m2b     = (const float*)d_in[12];
    const float* bias2   = (const float*)d_in[13];
    const float* nw2     = (const float*)d_in[14];
    const float* w3      = (const float*)d_in[15];
    const float* m3w     = (const float*)d_in[16];
    const float* m3b     = (const float*)d_in[17];
    const float* bias3   = (const float*)d_in[18];
    float* out = (float*)d_out;

    char* p = (char*)d_ws;
    auto alloc = [&](size_t bytes) { char* r = p; p += (bytes + 255) & ~(size_t)255; return r; };
    float* s1 = (float*)alloc(8 * 512 * 4);
    float* s2 = (float*)alloc(8 * 512 * 4);
    float* s3 = (float*)alloc(8 * 512 * 4);
    float* d1 = (float*)alloc(8 * 512 * 4);
    float* d2 = (float*)alloc(8 * 512 * 4);
    float* wsq1 = (float*)alloc((size_t)512 * 512 * 4);
    float* wsq2 = (float*)alloc((size_t)512 * 512 * 4);
    f16* wA1 = (f16*)alloc((size_t)9 * 512 * 512 * 2);
    f16* wA2 = (f16*)alloc((size_t)9 * 512 * 512 * 2);
    const size_t XMH_B  = (size_t)8 * 34 * 34 * 512 * 2;        //  9.47 MB
    const size_t CTP_B  = (size_t)8 * 68 * 68 * 512 * 2;        // 37.88 MB (NHWC)
    const size_t IN1H_B = (size_t)8 * 66 * 66 * 512 * 2;        // 35.69 MB
    char* ovl = (char*)alloc(XMH_B + CTP_B + IN1H_B);
    f16* xmh  = (f16*)ovl;
    f16* ctp  = (f16*)(ovl + XMH_B);
    f16* in1h = (f16*)(ovl + XMH_B + CTP_B);

    k_prep1<<<2840, 256, 0, stream>>>(style, m1w, m1b, m2w, m2b, m3w, m3b, s1, s2, s3,
                                      w1, w2, wA1, wA2, wsq1, wsq2, xmh, in1h, ctp,
                                      skiprgb, bias3, out);
    k_prep2<<<1280, 256, 0, stream>>>(wsq1, s1, d1, wsq2, s2, d2, x, xmh);
    k_conv1m<<<266, 512, 0, stream>>>(xmh, wA1, ctp);
    k_blur1<<<dim3(32, 8), 256, 0, stream>>>(ctp, d1, noise1, nw1, bias1, s2, in1h);
    k_conv2_8p<<<dim3(16, 2, 8), 512, 0, stream>>>(in1h, wA2, d2, noise2, nw2, bias2, s3, w3, out);
}

// Round 16
// 245.951 us; speedup vs baseline: 1.0293x; 1.0293x over previous
//
#include <hip/hip_runtime.h>

typedef _Float16 f16;
typedef __attribute__((ext_vector_type(4))) _Float16 f16x4;
typedef __attribute__((ext_vector_type(8))) _Float16 f16x8;
typedef __attribute__((ext_vector_type(4))) float f32x4;

#define SC_CONV 0.014731391274719738f   /* 1/sqrt(512*9) */
#define SC_RGB  0.04419417382415922f    /* 1/sqrt(512)   */
#define SC_LIN  0.04419417382415922f    /* 1/sqrt(512)   */
#define SQRT2F  1.4142135623730951f

__device__ inline f32x4 zero_f32x4() {
    f32x4 v;
    #pragma unroll
    for (int i = 0; i < 4; ++i) v[i] = 0.0f;
    return v;
}
__device__ inline void gload_lds16(const void* g, void* l) {
    __builtin_amdgcn_global_load_lds(
        (const __attribute__((address_space(1))) unsigned int*)g,
        (__attribute__((address_space(3))) unsigned int*)l, 16, 0, 0);
}

// ---- prep1: prep_w(+wsq) + styles(wave-per-o) + halos + ctp shell + out init ----------
__global__ __launch_bounds__(256) void k_prep1(
    const float* __restrict__ style,
    const float* __restrict__ m1w, const float* __restrict__ m1b,
    const float* __restrict__ m2w, const float* __restrict__ m2b,
    const float* __restrict__ m3w, const float* __restrict__ m3b,
    float* __restrict__ s1, float* __restrict__ s2, float* __restrict__ s3,
    const float* __restrict__ w1, const float* __restrict__ w2,
    f16* __restrict__ wA1, f16* __restrict__ wA2,
    float* __restrict__ wsq1, float* __restrict__ wsq2,
    f16* __restrict__ xmh, f16* __restrict__ in1h, f16* __restrict__ ctp,
    const float* __restrict__ skiprgb, const float* __restrict__ bias3,
    float* __restrict__ out)
{
    const int bx = blockIdx.x;
    if (bx < 2048) {
        int g = bx * 256 + threadIdx.x;     // over 2*512*512
        int set = g >> 18; int oi = g & 262143;
        const float* w = (set ? w2 : w1) + (size_t)oi * 9;
        f16* wa = set ? wA2 : wA1;
        float* wq = set ? wsq2 : wsq1;
        int o = oi >> 9, i = oi & 511;
        float sw = 0.f;
        #pragma unroll
        for (int t = 0; t < 9; ++t) {
            float v = w[t];
            wa[((size_t)t * 512 + o) * 512 + i] = (f16)v;
            sw += v * v;
        }
        wq[oi] = sw;
    } else if (bx < 2432) {
        const int lane = threadIdx.x & 63, wid = threadIdx.x >> 6;
        const int gw = (bx - 2048) * 4 + wid;
        const int set = gw >> 9, o = gw & 511;
        const float* mw = set == 0 ? m1w : set == 1 ? m2w : m3w;
        const float* mb = set == 0 ? m1b : set == 1 ? m2b : m3b;
        float* outp = set == 0 ? s1 : set == 1 ? s2 : s3;
        const float4 m0 = *(const float4*)(mw + (size_t)o * 512 + lane * 8);
        const float4 m1 = *(const float4*)(mw + (size_t)o * 512 + lane * 8 + 4);
        const float mv[8] = {m0.x, m0.y, m0.z, m0.w, m1.x, m1.y, m1.z, m1.w};
        float acc[8];
        #pragma unroll
        for (int b = 0; b < 8; ++b) {
            const float4 sA = *(const float4*)(style + b * 512 + lane * 8);
            const float4 sB = *(const float4*)(style + b * 512 + lane * 8 + 4);
            acc[b] = mv[0]*sA.x + mv[1]*sA.y + mv[2]*sA.z + mv[3]*sA.w
                   + mv[4]*sB.x + mv[5]*sB.y + mv[6]*sB.z + mv[7]*sB.w;
        }
        #pragma unroll
        for (int b = 0; b < 8; ++b)
            #pragma unroll
            for (int off = 1; off < 64; off <<= 1)
                acc[b] += __shfl_xor(acc[b], off);
        if (lane == 0) {
            const float mbv = mb[o];
            #pragma unroll
            for (int b = 0; b < 8; ++b) outp[b * 512 + o] = acc[b] * SC_LIN + mbv;
        }
    } else if (bx < 2448) {
        const int idx = bx - 2432, b = idx & 7, type = idx >> 3;
        f16x8 z;
        #pragma unroll
        for (int i = 0; i < 8; ++i) z[i] = (_Float16)0.0f;
        if (type == 0) {
            for (int j = threadIdx.x; j < 132 * 64; j += 256) {
                int pix = j >> 6, e = j & 63;
                int r, c;
                if (pix < 34)       { r = 0;            c = pix; }
                else if (pix < 68)  { r = 33;           c = pix - 34; }
                else if (pix < 100) { r = pix - 68 + 1; c = 0; }
                else                { r = pix - 100 + 1; c = 33; }
                *(f16x8*)(xmh + ((((size_t)b * 34 + r) * 34 + c) * 512) + e * 8) = z;
            }
        } else {
            for (int j = threadIdx.x; j < 260 * 64; j += 256) {
                int pix = j >> 6, e = j & 63;
                int r, c;
                if (pix < 66)       { r = 0;             c = pix; }
                else if (pix < 132) { r = 65;            c = pix - 66; }
                else if (pix < 196) { r = pix - 132 + 1; c = 0; }
                else                { r = pix - 196 + 1; c = 65; }
                *(f16x8*)(in1h + ((((size_t)b * 66 + r) * 66 + c) * 512) + e * 8) = z;
            }
        }
    } else if (bx < 2456) {
        const int b = bx - 2448;
        f16x8 z;
        #pragma unroll
        for (int i = 0; i < 8; ++i) z[i] = (_Float16)0.0f;
        for (int j = threadIdx.x; j < 266 * 64; j += 256) {
            int pix = j >> 6, e = j & 63;
            int r, c;
            if (pix < 68)       { r = 0;             c = pix; }
            else if (pix < 136) { r = 66;            c = pix - 68; }
            else if (pix < 201) { r = 1 + (pix - 136); c = 0; }
            else                { r = 1 + (pix - 201); c = 66; }
            *(f16x8*)(ctp + ((((size_t)b * 68 + r) * 68 + c) * 512) + e * 8) = z;
        }
    } else {
        const unsigned g = (unsigned)(bx - 2456) * 256 + threadIdx.x;  // < 98304
        const unsigned b = g / 12288u, rem = g - b * 12288u;
        const unsigned c = rem >> 12, pix = rem & 4095u;
        const int y = (int)(pix >> 6), xx = (int)(pix & 63);
        const float kk[4] = {1.f, 3.f, 3.f, 1.f};
        int sy = y & 1, sx = xx & 1;
        int u0 = ((y + sy) >> 1) - 1, v0 = ((xx + sx) >> 1) - 1;
        float cy0 = kk[sy], cy1 = kk[sy + 2], cx0 = kk[sx], cx1 = kk[sx + 2];
        float sk = 0.f;
        #pragma unroll
        for (int aa = 0; aa < 2; ++aa)
            #pragma unroll
            for (int bb = 0; bb < 2; ++bb) {
                int u = u0 + aa, vv = v0 + bb;
                if (u >= 0 && u < 32 && vv >= 0 && vv < 32)
                    sk += (aa ? cy1 : cy0) * (bb ? cx1 : cx0) *
                          skiprgb[(((size_t)b * 3 + c) * 32 + u) * 32 + vv];
            }
        out[(((size_t)b * 3 + c) * 64 + y) * 64 + xx] = bias3[c] + sk * (1.0f / 16.0f);
    }
}

// ---------------- prep2: demod (reads wsq) + prep_x ----------------
__global__ __launch_bounds__(256) void k_prep2(
    const float* __restrict__ wsq1, const float* __restrict__ s1, float* __restrict__ d1,
    const float* __restrict__ wsq2, const float* __restrict__ s2, float* __restrict__ d2,
    const float* __restrict__ x, f16* __restrict__ xmh)
{
    __shared__ float red[8][4];
    __shared__ float t[32][33];
    const int bx = blockIdx.x;
    if (bx < 1024) {
        const int o = bx & 511, set = bx >> 9;
        const float* wq = set ? wsq2 : wsq1;
        const float* s = set ? s2 : s1;
        float* d = set ? d2 : d1;
        float acc[8] = {0,0,0,0,0,0,0,0};
        for (int i = threadIdx.x; i < 512; i += 256) {
            const float sw = wq[(size_t)o * 512 + i];
            #pragma unroll
            for (int b = 0; b < 8; ++b) { float sv = s[b * 512 + i]; acc[b] += sv * sv * sw; }
        }
        const int lane = threadIdx.x & 63, wid = threadIdx.x >> 6;
        #pragma unroll
        for (int b = 0; b < 8; ++b)
            #pragma unroll
            for (int off = 1; off < 64; off <<= 1)
                acc[b] += __shfl_xor(acc[b], off);
        if (lane == 0) {
            #pragma unroll
            for (int b = 0; b < 8; ++b) red[b][wid] = acc[b];
        }
        __syncthreads();
        if (threadIdx.x < 8) {
            float s4 = red[threadIdx.x][0] + red[threadIdx.x][1] + red[threadIdx.x][2] + red[threadIdx.x][3];
            d[threadIdx.x * 512 + o] = rsqrtf(s4 * (SC_CONV * SC_CONV) + 1e-8f);
        }
    } else {
        const int idx = bx - 1024, u = idx & 31, b = idx >> 5;
        int tx = threadIdx.x & 31, ty = threadIdx.x >> 5;   // 32 x 8
        for (int ic = 0; ic < 512; ic += 32) {
            #pragma unroll
            for (int k = 0; k < 4; ++k) {
                int i = ic + ty + 8 * k;
                t[ty + 8 * k][tx] = x[(((size_t)b * 512 + i) * 32 + u) * 32 + tx];
            }
            __syncthreads();
            #pragma unroll
            for (int k = 0; k < 4; ++k) {
                int v = ty + 8 * k;
                int i = ic + tx;
                float sv = s1[b * 512 + i] * SC_CONV;
                xmh[(((size_t)b * 34 + u + 1) * 34 + v + 1) * 512 + i] = (f16)(t[tx][v] * sv);
            }
            __syncthreads();
        }
    }
}

// ---------------- conv1: batch-merged flattened 256-tile, two-phase pipeline ------------
__global__ __launch_bounds__(512, 2) void k_conv1m(
    const f16* __restrict__ xmh, const f16* __restrict__ wA1, f16* __restrict__ ctp)
{
    const int gid = blockIdx.x;
    int ph, tbase;
    if (gid < 70)       { ph = 0; tbase = 0; }
    else if (gid < 136) { ph = 1; tbase = 70; }
    else if (gid < 202) { ph = 2; tbase = 136; }
    else                { ph = 3; tbase = 202; }
    const int p = ph >> 1, q = ph & 1;
    const int Nn = q ? 32 : 33;
    const unsigned npos = (unsigned)((p ? 32 : 33) * Nn);
    const unsigned ntot = npos * 8;
    const int tiles_n = (int)((ntot + 255) >> 8);
    int t = gid - tbase;
    const int mB = (t >= tiles_n) ? 256 : 0;
    if (t >= tiles_n) t -= tiles_n;
    const unsigned posB = (unsigned)t * 256;
    const int ntx = q ? 1 : 2;
    const int ntaps = (p ? 1 : 2) * ntx;
    const int ktsteps = ntaps * 8;

    __shared__ f16 LA[2][16384];
    __shared__ f16 LB[2][16384];
    const int tid = threadIdx.x, lane = tid & 63, wid = tid >> 6;
    const int wm = wid >> 2, wn = wid & 3;      // 2 M-waves x 4 N-waves
    const int lr = lane & 15, lk = lane >> 4;

    f32x4 acc[8][4];
    #pragma unroll
    for (int mf = 0; mf < 8; ++mf)
        #pragma unroll
        for (int nf = 0; nf < 4; ++nf) acc[mf][nf] = zero_f32x4();

    int aoff[4], boff[4], ldst[4];
    #pragma unroll
    for (int c = 0; c < 4; ++c) {
        const int idx = c * 512 + tid;
        const int row = idx >> 3, sl = idx & 7, ssl = sl ^ (row & 7);
        ldst[c] = idx * 16;
        aoff[c] = (mB + row) * 512 + ssl * 8;
        unsigned pos = posB + (unsigned)row;
        if (pos > ntot - 1) pos = ntot - 1;
        const unsigned bb = pos / npos, rr = pos - bb * npos;
        const unsigned u = rr / (unsigned)Nn, v = rr - u * (unsigned)Nn;
        boff[c] = (int)(((bb * 34 + u + 1) * 34 + v + 1) * 512) + ssl * 8;
    }

    int raA[8], raB[4];
    #pragma unroll
    for (int mf = 0; mf < 8; ++mf) {
        const int R = wm * 128 + mf * 16 + lr;
        raA[mf] = R * 128 + ((lk ^ (R & 7)) * 16);
    }
    #pragma unroll
    for (int nf = 0; nf < 4; ++nf) {
        const int R = wn * 64 + nf * 16 + lr;
        raB[nf] = R * 128 + ((lk ^ (R & 7)) * 16);
    }

    auto stageA = [&](int kt, int d) {
        const int tt = kt >> 3, icb = (kt & 7) << 6;
        const int ay = (ntx == 2) ? (tt >> 1) : tt;
        const int ax = (ntx == 2) ? (tt & 1) : 0;
        const f16* base = wA1 + (size_t)((p + 2 * ay) * 3 + (q + 2 * ax)) * 262144 + icb;
        char* dst = (char*)LA[d];
        #pragma unroll
        for (int c = 0; c < 4; ++c)
            gload_lds16(base + aoff[c], dst + ldst[c]);
    };
    auto stageB = [&](int kt, int d) {
        const int tt = kt >> 3, icb = (kt & 7) << 6;
        const int ay = (ntx == 2) ? (tt >> 1) : tt;
        const int ax = (ntx == 2) ? (tt & 1) : 0;
        const f16* base = xmh - (long)(ay * 34 + ax) * 512 + icb;
        char* dst = (char*)LB[d];
        #pragma unroll
        for (int c = 0; c < 4; ++c)
            gload_lds16(base + boff[c], dst + ldst[c]);
    };

    stageB(0, 0);
    stageA(0, 0);
    for (int kt = 0; kt < ktsteps; ++kt) {
        const int d = kt & 1;
        asm volatile("s_waitcnt vmcnt(0)" ::: "memory");
        __builtin_amdgcn_s_barrier();
        const char* A = (const char*)LA[d];
        const char* Bm = (const char*)LB[d];
        f16x8 bf[4][2], af[4][2];
        #pragma unroll
        for (int nf = 0; nf < 4; ++nf) {
            bf[nf][0] = *(const f16x8*)(Bm + raB[nf]);
            bf[nf][1] = *(const f16x8*)(Bm + (raB[nf] ^ 64));
        }
        #pragma unroll
        for (int mf = 0; mf < 4; ++mf) {
            af[mf][0] = *(const f16x8*)(A + raA[mf]);
            af[mf][1] = *(const f16x8*)(A + (raA[mf] ^ 64));
        }
        if (kt + 1 < ktsteps) stageB(kt + 1, d ^ 1);
        asm volatile("s_waitcnt lgkmcnt(0)" ::: "memory");
        __builtin_amdgcn_sched_barrier(0);
        __builtin_amdgcn_s_setprio(1);
        #pragma unroll
        for (int mf = 0; mf < 4; ++mf)
            #pragma unroll
            for (int nf = 0; nf < 4; ++nf) {
                acc[mf][nf] = __builtin_amdgcn_mfma_f32_16x16x32_f16(
                    af[mf][0], bf[nf][0], acc[mf][nf], 0, 0, 0);
                acc[mf][nf] = __builtin_amdgcn_mfma_f32_16x16x32_f16(
                    af[mf][1], bf[nf][1], acc[mf][nf], 0, 0, 0);
            }
        __builtin_amdgcn_s_setprio(0);
        __builtin_amdgcn_s_barrier();
        #pragma unroll
        for (int mf = 0; mf < 4; ++mf) {
            af[mf][0] = *(const f16x8*)(A + raA[mf + 4]);
            af[mf][1] = *(const f16x8*)(A + (raA[mf + 4] ^ 64));
        }
        if (kt + 1 < ktsteps) stageA(kt + 1, d ^ 1);
        asm volatile("s_waitcnt lgkmcnt(0)" ::: "memory");
        __builtin_amdgcn_sched_barrier(0);
        __builtin_amdgcn_s_setprio(1);
        #pragma unroll
        for (int mf = 0; mf < 4; ++mf)
            #pragma unroll
            for (int nf = 0; nf < 4; ++nf) {
                acc[mf + 4][nf] = __builtin_amdgcn_mfma_f32_16x16x32_f16(
                    af[mf][0], bf[nf][0], acc[mf + 4][nf], 0, 0, 0);
                acc[mf + 4][nf] = __builtin_amdgcn_mfma_f32_16x16x32_f16(
                    af[mf][1], bf[nf][1], acc[mf + 4][nf], 0, 0, 0);
            }
        __builtin_amdgcn_s_setprio(0);
    }

    // epilogue: coalesced f16x4 NHWC stores
    #pragma unroll
    for (int nf = 0; nf < 4; ++nf) {
        const int c = wn * 64 + nf * 16 + lr;
        const unsigned pos = posB + (unsigned)c;
        if (pos >= ntot) continue;
        const unsigned bb = pos / npos, rr = pos - bb * npos;
        const unsigned u = rr / (unsigned)Nn, v = rr - u * (unsigned)Nn;
        const int row = 1 + 2 * (int)u + p, col = 1 + 2 * (int)v + q;
        f16* dst = ctp + (((size_t)bb * 68 + row) * 68 + col) * 512;
        #pragma unroll
        for (int mf = 0; mf < 8; ++mf) {
            const int ob = mB + wm * 128 + mf * 16 + lk * 4;
            f16x4 st;
            #pragma unroll
            for (int r = 0; r < 4; ++r) st[r] = (f16)acc[mf][nf][r];
            *(f16x4*)(dst + ob) = st;
        }
    }
}

// ---- blur1 (NHWC): 2-row blocks, vertical reuse, channel-on-lanes, no LDS --------------
__global__ __launch_bounds__(256) void k_blur1(
    const f16* __restrict__ ctp, const float* __restrict__ d1,
    const float* __restrict__ noise1, const float* __restrict__ nw1,
    const float* __restrict__ bias1, const float* __restrict__ s2,
    f16* __restrict__ in1h)
{
    const int y0 = blockIdx.x * 2, b = blockIdx.y;
    const int tx = threadIdx.x & 63, xg = threadIdx.x >> 6;
    const int ch = tx * 8, x0 = xg * 16;
    const f16* base = ctp + ((size_t)(b * 68 + y0) * 68) * 512 + ch;   // row y0, col 0

    float d1v[8], b1v[8], s2v[8];
    {
        const float4 a0 = *(const float4*)(d1 + b * 512 + ch);
        const float4 a1 = *(const float4*)(d1 + b * 512 + ch + 4);
        const float4 c0 = *(const float4*)(bias1 + ch);
        const float4 c1 = *(const float4*)(bias1 + ch + 4);
        const float4 e0 = *(const float4*)(s2 + b * 512 + ch);
        const float4 e1 = *(const float4*)(s2 + b * 512 + ch + 4);
        d1v[0]=a0.x; d1v[1]=a0.y; d1v[2]=a0.z; d1v[3]=a0.w;
        d1v[4]=a1.x; d1v[5]=a1.y; d1v[6]=a1.z; d1v[7]=a1.w;
        b1v[0]=c0.x; b1v[1]=c0.y; b1v[2]=c0.z; b1v[3]=c0.w;
        b1v[4]=c1.x; b1v[5]=c1.y; b1v[6]=c1.z; b1v[7]=c1.w;
        s2v[0]=e0.x; s2v[1]=e0.y; s2v[2]=e0.z; s2v[3]=e0.w;
        s2v[4]=e1.x; s2v[5]=e1.y; s2v[6]=e1.z; s2v[7]=e1.w;
    }
    const float nw = nw1[0];
    const float* nrow0 = noise1 + ((size_t)b * 64 + y0) * 64;
    const float* nrow1 = nrow0 + 64;

    float cs[4][2][8];
    #define LOADCOL(cc, slot)                                                   \
        do {                                                                    \
            f16x8 v0 = *(const f16x8*)(base + ((size_t)(0 * 68 + (cc))) * 512); \
            f16x8 v1 = *(const f16x8*)(base + ((size_t)(1 * 68 + (cc))) * 512); \
            f16x8 v2 = *(const f16x8*)(base + ((size_t)(2 * 68 + (cc))) * 512); \
            f16x8 v3 = *(const f16x8*)(base + ((size_t)(3 * 68 + (cc))) * 512); \
            f16x8 v4 = *(const f16x8*)(base + ((size_t)(4 * 68 + (cc))) * 512); \
            _Pragma("unroll")                                                   \
            for (int k = 0; k < 8; ++k) {                                       \
                float f0=(float)v0[k], f1=(float)v1[k], f2=(float)v2[k];        \
                float f3=(float)v3[k], f4=(float)v4[k];                         \
                cs[slot][0][k] = f0 + 3.f*f1 + 3.f*f2 + f3;                     \
                cs[slot][1][k] = f1 + 3.f*f2 + 3.f*f3 + f4;                     \
            }                                                                   \
        } while (0)

    LOADCOL(x0 + 0, 0);
    LOADCOL(x0 + 1, 1);
    LOADCOL(x0 + 2, 2);
    #pragma unroll
    for (int xi = 0; xi < 16; ++xi) {
        LOADCOL(x0 + xi + 3, ((xi + 3) & 3));
        const int x = x0 + xi;
        const float nz0 = nw * nrow0[x];
        const float nz1 = nw * nrow1[x];
        f16x8 st0, st1;
        #pragma unroll
        for (int k = 0; k < 8; ++k) {
            float s0 = (cs[xi & 3][0][k] + cs[(xi + 3) & 3][0][k])
                     + 3.f * (cs[(xi + 1) & 3][0][k] + cs[(xi + 2) & 3][0][k]);
            float v0 = s0 * (1.0f / 16.0f) * d1v[k] + nz0 + b1v[k];
            v0 = (v0 > 0.f ? v0 : 0.2f * v0) * SQRT2F;
            st0[k] = (f16)(v0 * s2v[k] * SC_CONV);
            float s1r = (cs[xi & 3][1][k] + cs[(xi + 3) & 3][1][k])
                      + 3.f * (cs[(xi + 1) & 3][1][k] + cs[(xi + 2) & 3][1][k]);
            float v1 = s1r * (1.0f / 16.0f) * d1v[k] + nz1 + b1v[k];
            v1 = (v1 > 0.f ? v1 : 0.2f * v1) * SQRT2F;
            st1[k] = (f16)(v1 * s2v[k] * SC_CONV);
        }
        *(f16x8*)(in1h + (((size_t)(b * 66 + 1 + y0) * 66) + 1 + x) * 512 + ch) = st0;
        *(f16x8*)(in1h + (((size_t)(b * 66 + 2 + y0) * 66) + 1 + x) * 512 + ch) = st1;
    }
    #undef LOADCOL
}

// ---- conv2: 256x256 tile, 8-wave, BK=64, two-phase pipeline + fused ToRGB epilogue -----
__global__ __launch_bounds__(512, 2) void k_conv2_8p(
    const f16* __restrict__ in1h, const f16* __restrict__ wA2,
    const float* __restrict__ d2, const float* __restrict__ noise2,
    const float* __restrict__ nw2, const float* __restrict__ bias2,
    const float* __restrict__ s3, const float* __restrict__ w3,
    float* __restrict__ out)
{
    const int b = blockIdx.z, mB = blockIdx.y * 256, nT = blockIdx.x;
    const int y0 = nT * 4;       // 256 pixels = rows y0..y0+3
    __shared__ f16 LA[2][16384];
    __shared__ f16 LB[2][16384];
    const int tid = threadIdx.x, lane = tid & 63, wid = tid >> 6;
    const int wm = wid >> 2, wn = wid & 3;      // 2 M-waves x 4 N-waves
    const int lr = lane & 15, lk = lane >> 4;

    f32x4 acc[8][4];
    #pragma unroll
    for (int mf = 0; mf < 8; ++mf)
        #pragma unroll
        for (int nf = 0; nf < 4; ++nf) acc[mf][nf] = zero_f32x4();

    int aoff[4], boff[4], ldst[4];
    #pragma unroll
    for (int c = 0; c < 4; ++c) {
        const int idx = c * 512 + tid;
        const int row = idx >> 3, sl = idx & 7, ssl = sl ^ (row & 7);
        ldst[c] = idx * 16;
        aoff[c] = (mB + row) * 512 + ssl * 8;
        const int py = y0 + (row >> 6), px = row & 63;
        boff[c] = ((b * 66 + 1 + py) * 66 + 1 + px) * 512 + ssl * 8;
    }

    int raA[8], raB[4];
    #pragma unroll
    for (int mf = 0; mf < 8; ++mf) {
        const int R = wm * 128 + mf * 16 + lr;
        raA[mf] = R * 128 + ((lk ^ (R & 7)) * 16);
    }
    #pragma unroll
    for (int nf = 0; nf < 4; ++nf) {
        const int R = wn * 64 + nf * 16 + lr;
        raB[nf] = R * 128 + ((lk ^ (R & 7)) * 16);
    }

    auto stageA = [&](int kt, int d) {
        const int tap = kt >> 3, icb = (kt & 7) << 6;
        const f16* base = wA2 + (size_t)tap * 262144 + icb;
        char* dst = (char*)LA[d];
        #pragma unroll
        for (int c = 0; c < 4; ++c)
            gload_lds16(base + aoff[c], dst + ldst[c]);
    };
    auto stageB = [&](int kt, int d) {
        const int tap = kt >> 3, icb = (kt & 7) << 6;
        const int dy = tap / 3 - 1, dx = tap - (tap / 3) * 3 - 1;
        const f16* base = in1h + (dy * 66 + dx) * 512 + icb;
        char* dst = (char*)LB[d];
        #pragma unroll
        for (int c = 0; c < 4; ++c)
            gload_lds16(base + boff[c], dst + ldst[c]);
    };

    stageB(0, 0);
    stageA(0, 0);
    for (int kt = 0; kt < 72; ++kt) {
        const int d = kt & 1;
        asm volatile("s_waitcnt vmcnt(0)" ::: "memory");
        __builtin_amdgcn_s_barrier();
        const char* A = (const char*)LA[d];
        const char* Bm = (const char*)LB[d];
        f16x8 bf[4][2], af[4][2];
        #pragma unroll
        for (int nf = 0; nf < 4; ++nf) {
            bf[nf][0] = *(const f16x8*)(Bm + raB[nf]);
            bf[nf][1] = *(const f16x8*)(Bm + (raB[nf] ^ 64));
        }
        #pragma unroll
        for (int mf = 0; mf < 4; ++mf) {
            af[mf][0] = *(const f16x8*)(A + raA[mf]);
            af[mf][1] = *(const f16x8*)(A + (raA[mf] ^ 64));
        }
        if (kt + 1 < 72) stageB(kt + 1, d ^ 1);
        asm volatile("s_waitcnt lgkmcnt(0)" ::: "memory");
        __builtin_amdgcn_sched_barrier(0);
        __builtin_amdgcn_s_setprio(1);
        #pragma unroll
        for (int mf = 0; mf < 4; ++mf)
            #pragma unroll
            for (int nf = 0; nf < 4; ++nf) {
                acc[mf][nf] = __builtin_amdgcn_mfma_f32_16x16x32_f16(
                    af[mf][0], bf[nf][0], acc[mf][nf], 0, 0, 0);
                acc[mf][nf] = __builtin_amdgcn_mfma_f32_16x16x32_f16(
                    af[mf][1], bf[nf][1], acc[mf][nf], 0, 0, 0);
            }
        __builtin_amdgcn_s_setprio(0);
        __builtin_amdgcn_s_barrier();
        #pragma unroll
        for (int mf = 0; mf < 4; ++mf) {
            af[mf][0] = *(const f16x8*)(A + raA[mf + 4]);
            af[mf][1] = *(const f16x8*)(A + (raA[mf + 4] ^ 64));
        }
        if (kt + 1 < 72) stageA(kt + 1, d ^ 1);
        asm volatile("s_waitcnt lgkmcnt(0)" ::: "memory");
        __builtin_amdgcn_sched_barrier(0);
        __builtin_amdgcn_s_setprio(1);
        #pragma unroll
        for (int mf = 0; mf < 4; ++mf)
            #pragma unroll
            for (int nf = 0; nf < 4; ++nf) {
                acc[mf + 4][nf] = __builtin_amdgcn_mfma_f32_16x16x32_f16(
                    af[mf][0], bf[nf][0], acc[mf + 4][nf], 0, 0, 0);
                acc[mf + 4][nf] = __builtin_amdgcn_mfma_f32_16x16x32_f16(
                    af[mf][1], bf[nf][1], acc[mf + 4][nf], 0, 0, 0);
            }
        __builtin_amdgcn_s_setprio(0);
    }

    // fused epilogue: demod+noise+bias+lrelu+s3 fold, then partial RGB dot + atomicAdd
    const float* d2b = d2 + b * 512;
    const float* s3b = s3 + b * 512;
    const float nw = nw2[0];
    float p3[4][3];
    #pragma unroll
    for (int nf = 0; nf < 4; ++nf)
        #pragma unroll
        for (int c = 0; c < 3; ++c) p3[nf][c] = 0.f;
    #pragma unroll
    for (int mf = 0; mf < 8; ++mf) {
        const int ob = mB + wm * 128 + mf * 16 + lk * 4;
        const float4 dv = *(const float4*)(d2b + ob);
        const float4 bv = *(const float4*)(bias2 + ob);
        const float4 sv = *(const float4*)(s3b + ob);
        const float4 w0 = *(const float4*)(w3 + 0 * 512 + ob);
        const float4 w1v = *(const float4*)(w3 + 1 * 512 + ob);
        const float4 w2v = *(const float4*)(w3 + 2 * 512 + ob);
        const float dd[4] = {dv.x, dv.y, dv.z, dv.w};
        const float bb[4] = {bv.x, bv.y, bv.z, bv.w};
        const float ss[4] = {sv.x, sv.y, sv.z, sv.w};
        const float w0r[4] = {w0.x, w0.y, w0.z, w0.w};
        const float w1r[4] = {w1v.x, w1v.y, w1v.z, w1v.w};
        const float w2r[4] = {w2v.x, w2v.y, w2v.z, w2v.w};
        #pragma unroll
        for (int nf = 0; nf < 4; ++nf) {
            const int c = wn * 64 + nf * 16 + lr;
            const int py = y0 + (c >> 6), px = c & 63;
            const float nz = nw * noise2[((size_t)b * 64 + py) * 64 + px];
            #pragma unroll
            for (int r = 0; r < 4; ++r) {
                float v = acc[mf][nf][r] * dd[r] + nz + bb[r];
                v = (v > 0.f ? v : 0.2f * v) * SQRT2F;
                v *= ss[r] * SC_RGB;
                p3[nf][0] += v * w0r[r];
                p3[nf][1] += v * w1r[r];
                p3[nf][2] += v * w2r[r];
            }
        }
    }
    #pragma unroll
    for (int nf = 0; nf < 4; ++nf)
        #pragma unroll
        for (int c = 0; c < 3; ++c) {
            float v = p3[nf][c];
            v += __shfl_xor(v, 16);
            v += __shfl_xor(v, 32);
            p3[nf][c] = v;
        }
    if (lk == 0) {
        #pragma unroll
        for (int nf = 0; nf < 4; ++nf) {
            const int c = wn * 64 + nf * 16 + lr;
            const int py = y0 + (c >> 6), px = c & 63;
            #pragma unroll
            for (int ch = 0; ch < 3; ++ch)
                atomicAdd(out + (((size_t)b * 3 + ch) * 64 + py) * 64 + px, p3[nf][ch]);
        }
    }
}

extern "C" void kernel_launch(void* const* d_in, const int* in_sizes, int n_in,
                              void* d_out, int out_size, void* d_ws, size_t ws_size,
                              hipStream_t stream)
{
    const float* x       = (const float*)d_in[0];
    const float* style   = (const float*)d_in[1];
    const float* skiprgb = (const float*)d_in[2];
    const float* noise1  = (const float*)d_in[3];
    const float* noise2  = (const float*)d_in[4];
    const float* w1      = (const float*)d_in[5];
    const float* m1w     = (const float*)d_in[6];
    const float* m1b     = (const float*)d_in[7];
    const float* bias1   = (const float*)d_in[8];
    const float* nw1     = (const float*)d_in[9];
    const float* w2      = (const float*)d_in[10];
    const float* m2w     = (const float*)d_in[11];
    const float* m2b     = (const float*)d_in[12];
    const float* bias2   = (const float*)d_in[13];
    const float* nw2     = (const float*)d_in[14];
    const float* w3      = (const float*)d_in[15];
    const float* m3w     = (const float*)d_in[16];
    const float* m3b     = (const float*)d_in[17];
    const float* bias3   = (const float*)d_in[18];
    float* out = (float*)d_out;

    char* p = (char*)d_ws;
    auto alloc = [&](size_t bytes) { char* r = p; p += (bytes + 255) & ~(size_t)255; return r; };
    float* s1 = (float*)alloc(8 * 512 * 4);
    float* s2 = (float*)alloc(8 * 512 * 4);
    float* s3 = (float*)alloc(8 * 512 * 4);
    float* d1 = (float*)alloc(8 * 512 * 4);
    float* d2 = (float*)alloc(8 * 512 * 4);
    float* wsq1 = (float*)alloc((size_t)512 * 512 * 4);
    float* wsq2 = (float*)alloc((size_t)512 * 512 * 4);
    f16* wA1 = (f16*)alloc((size_t)9 * 512 * 512 * 2);
    f16* wA2 = (f16*)alloc((size_t)9 * 512 * 512 * 2);
    const size_t XMH_B  = (size_t)8 * 34 * 34 * 512 * 2;        //  9.47 MB
    const size_t CTP_B  = (size_t)8 * 68 * 68 * 512 * 2;        // 37.88 MB (NHWC)
    const size_t IN1H_B = (size_t)8 * 66 * 66 * 512 * 2;        // 35.69 MB
    char* ovl = (char*)alloc(XMH_B + CTP_B + IN1H_B);
    f16* xmh  = (f16*)ovl;
    f16* ctp  = (f16*)(ovl + XMH_B);
    f16* in1h = (f16*)(ovl + XMH_B + CTP_B);

    k_prep1<<<2840, 256, 0, stream>>>(style, m1w, m1b, m2w, m2b, m3w, m3b, s1, s2, s3,
                                      w1, w2, wA1, wA2, wsq1, wsq2, xmh, in1h, ctp,
                                      skiprgb, bias3, out);
    k_prep2<<<1280, 256, 0, stream>>>(wsq1, s1, d1, wsq2, s2, d2, x, xmh);
    k_conv1m<<<266, 512, 0, stream>>>(xmh, wA1, ctp);
    k_blur1<<<dim3(32, 8), 256, 0, stream>>>(ctp, d1, noise1, nw1, bias1, s2, in1h);
    k_conv2_8p<<<dim3(16, 2, 8), 512, 0, stream>>>(in1h, wA2, d2, noise2, nw2, bias2, s3, w3, out);
}